// Round 9
// baseline (158.440 us; speedup 1.0000x reference)
//
#include <hip/hip_runtime.h>

// ---------------------------------------------------------------------------
// Kernel 1: per-Gaussian preprocessing. 64-thread blocks. Writes areas,
// unsorted param SoA, depth sort keys, zero-inits rank + bin counters + nBig.
// ---------------------------------------------------------------------------
__global__ __launch_bounds__(64) void k_pre(
    const float* __restrict__ pws, const float* __restrict__ shs,
    const float* __restrict__ alphas_raw, const float* __restrict__ scales_raw,
    const float* __restrict__ rots_raw, const float* __restrict__ Rcw,
    const float* __restrict__ tcw, const float* __restrict__ intr,
    int N, int W, int H, float* __restrict__ areas,
    unsigned long long* __restrict__ keys, unsigned* __restrict__ rank,
    float* __restrict__ P, unsigned* __restrict__ cnts, int nCntTot)
{
    int i = blockIdx.x * 64 + threadIdx.x;
    if (i >= N) return;
    rank[i] = 0u;
    for (int z = i; z < nCntTot; z += N) cnts[z] = 0u;

    float R00=Rcw[0],R01=Rcw[1],R02=Rcw[2];
    float R10=Rcw[3],R11=Rcw[4],R12=Rcw[5];
    float R20=Rcw[6],R21=Rcw[7],R22=Rcw[8];
    float t0=tcw[0],t1=tcw[1],t2=tcw[2];
    float fx=intr[0],fy=intr[1],cx=intr[2],cy=intr[3];

    float pwx=pws[i*3+0], pwy=pws[i*3+1], pwz=pws[i*3+2];
    float pcx = R00*pwx + R01*pwy + R02*pwz + t0;
    float pcy = R10*pwx + R11*pwy + R12*pwz + t1;
    float pcz = R20*pwx + R21*pwy + R22*pwz + t2;
    float depth = pcz;
    float zs = (depth > 0.2f) ? depth : 1.0f;
    float u0 = fx * pcx / zs + cx;
    float u1 = fy * pcy / zs + cy;

    float4 q4 = *reinterpret_cast<const float4*>(rots_raw + i*4);
    float qw=q4.x, qx=q4.y, qy=q4.z, qz=q4.w;
    float qn = sqrtf(qw*qw + qx*qx + qy*qy + qz*qz);
    qw/=qn; qx/=qn; qy/=qn; qz/=qn;
    float s0 = expf(scales_raw[i*3+0]);
    float s1 = expf(scales_raw[i*3+1]);
    float s2 = expf(scales_raw[i*3+2]);

    float xx=qx*qx, yy=qy*qy, zq=qz*qz;
    float xy=qx*qy, xz=qx*qz, yz=qy*qz;
    float wx=qw*qx, wy=qw*qy, wz=qw*qz;
    float r00=1.f-2.f*(yy+zq), r01=2.f*(xy-wz),     r02=2.f*(xz+wy);
    float r10=2.f*(xy+wz),     r11=1.f-2.f*(xx+zq), r12=2.f*(yz-wx);
    float r20=2.f*(xz-wy),     r21=2.f*(yz+wx),     r22=1.f-2.f*(xx+yy);

    float m00=r00*s0, m01=r01*s1, m02=r02*s2;
    float m10=r10*s0, m11=r11*s1, m12=r12*s2;
    float m20=r20*s0, m21=r21*s1, m22=r22*s2;
    float V00=m00*m00+m01*m01+m02*m02;
    float V01=m00*m10+m01*m11+m02*m12;
    float V02=m00*m20+m01*m21+m02*m22;
    float V11=m10*m10+m11*m11+m12*m12;
    float V12=m10*m20+m11*m21+m12*m22;
    float V22=m20*m20+m21*m21+m22*m22;

    float tanfx = (float)W / (2.f*fx), tanfy = (float)H / (2.f*fy);
    float limx = 1.3f*tanfx, limy = 1.3f*tanfy;
    float txl = fminf(fmaxf(pcx/zs, -limx), limx) * zs;
    float tyl = fminf(fmaxf(pcy/zs, -limy), limy) * zs;
    float iz = 1.f/zs, iz2 = iz*iz;
    float J00 = fx*iz, J02 = -fx*txl*iz2;
    float J11 = fy*iz, J12 = -fy*tyl*iz2;

    float T00=J00*R00+J02*R20, T01=J00*R01+J02*R21, T02=J00*R02+J02*R22;
    float T10=J11*R10+J12*R20, T11=J11*R11+J12*R21, T12=J11*R12+J12*R22;
    float A0=T00*V00+T01*V01+T02*V02;
    float A1=T00*V01+T01*V11+T02*V12;
    float A2=T00*V02+T01*V12+T02*V22;
    float B0=T10*V00+T11*V01+T12*V02;
    float B1=T10*V01+T11*V11+T12*V12;
    float B2=T10*V02+T11*V12+T12*V22;
    float ca = A0*T00+A1*T01+A2*T02 + 0.3f;
    float cb = A0*T10+A1*T11+A2*T12;
    float cc = B0*T10+B1*T11+B2*T12 + 0.3f;

    float det = ca*cc - cb*cb;
    bool valid = (depth > 0.2f) && (det > 0.f);
    float det_s = valid ? det : 1.f;
    float dinv = 1.f/det_s;
    float ci0 =  cc*dinv, ci1 = -cb*dinv, ci2 = ca*dinv;
    float mid = 0.5f*(ca+cc);
    float lam = mid + sqrtf(fmaxf(mid*mid - det, 0.1f));
    float radius = valid ? ceilf(3.f*sqrtf(lam)) : 0.f;
    areas[2*i+0] = radius;
    areas[2*i+1] = radius;

    float alpha = 1.f/(1.f + expf(-alphas_raw[i]));

    float tw0 = -(R00*t0 + R10*t1 + R20*t2);
    float tw1 = -(R01*t0 + R11*t1 + R21*t2);
    float tw2 = -(R02*t0 + R12*t1 + R22*t2);
    float dx_=pwx-tw0, dy_=pwy-tw1, dz_=pwz-tw2;
    float dn = sqrtf(dx_*dx_+dy_*dy_+dz_*dz_);
    float x=dx_/dn, y=dy_/dn, z=dz_/dn;
    float sxx=x*x, syy=y*y, szz=z*z;
    float sxy=x*y, syz=y*z, sxz=x*z;

    float shl[48];
    const float4* sh4 = reinterpret_cast<const float4*>(shs + i*48);
    #pragma unroll
    for (int k = 0; k < 12; ++k) {
        float4 v = sh4[k];
        shl[4*k+0]=v.x; shl[4*k+1]=v.y; shl[4*k+2]=v.z; shl[4*k+3]=v.w;
    }
    float col[3];
    #pragma unroll
    for (int c = 0; c < 3; ++c) {
        float res = 0.28209479177387814f*shl[0*3+c];
        res += -0.4886025119029199f*y*shl[1*3+c]
             +  0.4886025119029199f*z*shl[2*3+c]
             + -0.4886025119029199f*x*shl[3*3+c];
        res +=  1.0925484305920792f*sxy*shl[4*3+c]
             + -1.0925484305920792f*syz*shl[5*3+c]
             +  0.31539156525252005f*(2.f*szz-sxx-syy)*shl[6*3+c]
             + -1.0925484305920792f*sxz*shl[7*3+c]
             +  0.5462742152960396f*(sxx-syy)*shl[8*3+c];
        res += -0.5900435899266435f*y*(3.f*sxx-syy)*shl[9*3+c]
             +  2.890611442640554f*sxy*z*shl[10*3+c]
             + -0.4570457994644658f*y*(4.f*szz-sxx-syy)*shl[11*3+c]
             +  0.3731763325901154f*z*(2.f*szz-3.f*sxx-3.f*syy)*shl[12*3+c]
             + -0.4570457994644658f*x*(4.f*szz-sxx-syy)*shl[13*3+c]
             +  1.445305721320277f*z*(sxx-syy)*shl[14*3+c]
             + -0.5900435899266435f*x*(sxx-3.f*syy)*shl[15*3+c];
        col[c] = fmaxf(res + 0.5f, 0.f);
    }

    float rc2;
    if (!valid || 255.f*alpha < 0.999f) {
        rc2 = -1.f;
    } else {
        float r2 = 2.f*lam*logf(255.f*alpha);
        float r  = sqrtf(fmaxf(r2, 0.f)) + 1.f;
        rc2 = r*r;
    }

    P[0*N+i]=u0;  P[1*N+i]=u1;  P[2*N+i]=ci0; P[3*N+i]=ci1; P[4*N+i]=ci2;
    P[5*N+i]=alpha; P[6*N+i]=col[0]; P[7*N+i]=col[1]; P[8*N+i]=col[2];
    P[9*N+i]=rc2;

    unsigned ud = __float_as_uint(depth);
    ud = (ud & 0x80000000u) ? ~ud : (ud | 0x80000000u);
    keys[i] = ((unsigned long long)ud << 32) | (unsigned)i;
}

// ---------------------------------------------------------------------------
// Kernel 2: O(N^2) rank sort fused with scatter ONLY (r6 form -- r8 lesson:
// welding binning onto the last-arrival path makes every wave wait on the
// rank-atomic return for the ballot and concentrates expansion in a
// near-serial tail; binning moved to k_bin/k_bin_big on sorted arrays).
// ---------------------------------------------------------------------------
#define JC 512
#define BCAP 64
__global__ __launch_bounds__(256) void k_rank_scatter(
    const unsigned long long* __restrict__ keys, int N,
    unsigned* __restrict__ rank, const float* __restrict__ Pun,
    float4* __restrict__ gA, float4* __restrict__ gB,
    float4* __restrict__ cull)
{
    __shared__ unsigned long long sk[JC];
    const int j0 = blockIdx.y * JC;
    const int nJ = gridDim.y;
    for (int t = threadIdx.x; t < JC; t += 256) {
        int j = j0 + t;
        sk[t] = (j < N) ? keys[j] : ~0ull;
    }
    __syncthreads();

    const int i = blockIdx.x * 256 + threadIdx.x;
    unsigned long long my = (i < N) ? keys[i] : 0ull;

    int c = 0;
    const ulonglong2* sk2 = (const ulonglong2*)sk;
    #pragma unroll 4
    for (int t = 0; t < JC/2; ++t) {
        ulonglong2 kk = sk2[t];
        c += (kk.x < my) ? 1 : 0;
        c += (kk.y < my) ? 1 : 0;
    }
    if (i < N) {
        unsigned old = atomicAdd(&rank[i], (unsigned)c + (1u << 20));
        if ((int)(old >> 20) == nJ - 1) {
            int s = (int)(old & 0xFFFFFu) + c;
            cull[s] = make_float4(Pun[0*N+i], Pun[1*N+i], Pun[9*N+i], 0.f);
            gA[s]   = make_float4(Pun[2*N+i], Pun[3*N+i], Pun[4*N+i], Pun[5*N+i]);
            gB[s]   = make_float4(Pun[6*N+i], Pun[7*N+i], Pun[8*N+i], 0.f);
        }
    }
}

// ---------------------------------------------------------------------------
// Kernel 3: binning from the SORTED cull array (no atomic-return dependency,
// no wave ballots on the critical path). Thread s: footprint <= SMALLT tiles
// -> walk lane-serially (pipelined atomics); else one append to bigList.
// ---------------------------------------------------------------------------
#define SMALLT 8
__global__ __launch_bounds__(256) void k_bin(
    const float4* __restrict__ cull, int N,
    int tilesX, int tilesY, int nseg, int W, int H,
    unsigned* __restrict__ cnts, int* __restrict__ list,
    int* __restrict__ bigList, unsigned* __restrict__ bigCnt)
{
    int s = blockIdx.x * 256 + threadIdx.x;
    if (s >= N) return;
    float4 cu = cull[s];
    float u0 = cu.x, u1 = cu.y, rc2 = cu.z;
    if (rc2 <= 0.f) return;

    const int per = (N + nseg - 1) / nseg;
    const int seg = s / per;
    float rr = sqrtf(rc2);
    int x0 = (int)fminf(fmaxf(floorf((u0 - rr) * 0.125f), 0.f), (float)(tilesX - 1));
    int x1 = (int)fminf(fmaxf(floorf((u0 + rr) * 0.125f), 0.f), (float)(tilesX - 1));
    int y0 = (int)fminf(fmaxf(floorf((u1 - rr) * 0.125f), 0.f), (float)(tilesY - 1));
    int y1 = (int)fminf(fmaxf(floorf((u1 + rr) * 0.125f), 0.f), (float)(tilesY - 1));
    int tot = (x1 - x0 + 1) * (y1 - y0 + 1);

    if (tot > SMALLT) {
        unsigned p = atomicAdd(bigCnt, 1u);
        bigList[p] = s;            // capacity N: each splat appends at most once
        return;
    }
    for (int ty = y0; ty <= y1; ++ty) {
        float by0f = (float)(ty << 3);
        float by1f = fminf(by0f + 7.f, (float)(H - 1));
        float cyp  = fminf(fmaxf(u1, by0f), by1f);
        float ddy  = u1 - cyp;
        for (int tx = x0; tx <= x1; ++tx) {
            float bx0f = (float)(tx << 3);
            float bx1f = fminf(bx0f + 7.f, (float)(W - 1));
            float cxp  = fminf(fmaxf(u0, bx0f), bx1f);
            float ddx  = u0 - cxp;
            if (ddx*ddx + ddy*ddy <= rc2) {
                int lid = (ty * tilesX + tx) * nseg + seg;
                unsigned pos = atomicAdd(&cnts[lid], 1u);
                if (pos < (unsigned)BCAP) list[lid * BCAP + (int)pos] = s;
            }
        }
    }
}

// ---------------------------------------------------------------------------
// Kernel 3b: big-footprint splats, block-parallel expansion. Block b walks
// bigList[b], b+64, ... with all 256 threads striding the bbox tiles.
// A 1024-tile monster = 4 atomics/thread. Order in lists is irrelevant
// (render bitonic-sorts by rank).
// ---------------------------------------------------------------------------
__global__ __launch_bounds__(256) void k_bin_big(
    const float4* __restrict__ cull, int N,
    const int* __restrict__ bigList, const unsigned* __restrict__ bigCnt,
    int tilesX, int tilesY, int nseg, int W, int H,
    unsigned* __restrict__ cnts, int* __restrict__ list)
{
    const int nBig = (int)*bigCnt;
    const int per = (N + nseg - 1) / nseg;
    for (int b = blockIdx.x; b < nBig; b += gridDim.x) {
        int s = bigList[b];
        float4 cu = cull[s];
        float u0 = cu.x, u1 = cu.y, rc2 = cu.z;
        const int seg = s / per;
        float rr = sqrtf(rc2);
        int x0 = (int)fminf(fmaxf(floorf((u0 - rr) * 0.125f), 0.f), (float)(tilesX - 1));
        int x1 = (int)fminf(fmaxf(floorf((u0 + rr) * 0.125f), 0.f), (float)(tilesX - 1));
        int y0 = (int)fminf(fmaxf(floorf((u1 - rr) * 0.125f), 0.f), (float)(tilesY - 1));
        int y1 = (int)fminf(fmaxf(floorf((u1 + rr) * 0.125f), 0.f), (float)(tilesY - 1));
        int nx  = x1 - x0 + 1;
        int tot = nx * (y1 - y0 + 1);
        for (int t = threadIdx.x; t < tot; t += 256) {
            int tx = x0 + (t % nx);
            int ty = y0 + (t / nx);
            float by0f = (float)(ty << 3);
            float by1f = fminf(by0f + 7.f, (float)(H - 1));
            float cyp  = fminf(fmaxf(u1, by0f), by1f);
            float ddy  = u1 - cyp;
            float bx0f = (float)(tx << 3);
            float bx1f = fminf(bx0f + 7.f, (float)(W - 1));
            float cxp  = fminf(fmaxf(u0, bx0f), bx1f);
            float ddx  = u0 - cxp;
            if (ddx*ddx + ddy*ddy <= rc2) {
                int lid = (ty * tilesX + tx) * nseg + seg;
                unsigned pos = atomicAdd(&cnts[lid], 1u);
                if (pos < (unsigned)BCAP) list[lid * BCAP + (int)pos] = s;
            }
        }
    }
}

// ---------------------------------------------------------------------------
// Kernel 4: binned render (unchanged from r8, validated). One wave per
// (8x8 tile, seg). Bitonic sort restores depth order; shfl-broadcast
// composite; overflow (cnt > BCAP) falls back to full-segment scan.
// ---------------------------------------------------------------------------
__global__ __launch_bounds__(64) void k_render(
    const float4* __restrict__ gA, const float4* __restrict__ gB,
    const float4* __restrict__ cull, const unsigned* __restrict__ cnts,
    const int* __restrict__ list, int N, int W, int H,
    int nTiles, int nseg, float4* __restrict__ segbuf)
{
    const int lane = threadIdx.x;
    const int tilesX = (W + 7) >> 3;
    const int tile = blockIdx.x % nTiles, seg = blockIdx.x / nTiles;
    const int tX = tile % tilesX, tY = tile / tilesX;
    const int ix = (tX << 3) + (lane & 7);
    const int iy = (tY << 3) + (lane >> 3);
    const bool inb = (ix < W) && (iy < H);
    const float pxf = (float)ix, pyf = (float)iy;

    float T = inb ? 1.f : 0.f;
    float aR = 0.f, aG = 0.f, aB = 0.f;

    const int lid = tile * nseg + seg;
    int cnt = (int)cnts[lid];

    if (cnt <= BCAP) {
        int v = (lane < cnt) ? list[lid * BCAP + lane] : 0x7FFFFFFF;
        #pragma unroll
        for (int k = 2; k <= 64; k <<= 1) {
            #pragma unroll
            for (int j = k >> 1; j > 0; j >>= 1) {
                int other = __shfl_xor(v, j);
                bool up = ((lane & k) == 0);
                bool takeMax = (((lane & j) != 0) == up);
                v = takeMax ? max(v, other) : min(v, other);
            }
        }
        float4 cu = make_float4(0.f,0.f,0.f,0.f);
        float4 a4 = make_float4(0.f,0.f,0.f,0.f);
        float4 b4 = make_float4(0.f,0.f,0.f,0.f);
        if (lane < cnt) { cu = cull[v]; a4 = gA[v]; b4 = gB[v]; }
        for (int e = 0; e < cnt; ++e) {
            float su0 = __shfl(cu.x, e), su1 = __shfl(cu.y, e);
            float ci0 = __shfl(a4.x, e), ci1 = __shfl(a4.y, e);
            float ci2 = __shfl(a4.z, e), sal = __shfl(a4.w, e);
            float cr  = __shfl(b4.x, e), cg  = __shfl(b4.y, e);
            float cbv = __shfl(b4.z, e);
            float ddx = pxf - su0, ddy = pyf - su1;
            float power = -0.5f*(ci0*ddx*ddx + ci2*ddy*ddy) - ci1*ddx*ddy;
            float alp = fminf(0.99f, sal * __expf(power));
            alp = (power <= 0.f && alp >= (1.0f/255.0f)) ? alp : 0.f;
            float w = (T > 0.0001f) ? alp * T : 0.f;
            aR = fmaf(w, cr, aR);
            aG = fmaf(w, cg, aG);
            aB = fmaf(w, cbv, aB);
            T = T - T * alp;
        }
    } else {
        const float tx0 = (float)(tX << 3), ty0 = (float)(tY << 3);
        int tx1i = (tX << 3) + 7; if (tx1i > W-1) tx1i = W-1;
        int ty1i = (tY << 3) + 7; if (ty1i > H-1) ty1i = H-1;
        const float tx1 = (float)tx1i, ty1 = (float)ty1i;
        const int per = (N + nseg - 1) / nseg;
        const int g0 = seg * per;
        const int g1 = min(N, g0 + per);
        for (int base = g0; base < g1; base += 64) {
            int g = base + lane;
            bool ov = false;
            float4 cu = make_float4(0.f,0.f,0.f,0.f);
            float4 a4 = make_float4(0.f,0.f,0.f,0.f);
            float4 b4 = make_float4(0.f,0.f,0.f,0.f);
            if (g < g1) {
                cu = cull[g];
                float cxp = fminf(fmaxf(cu.x, tx0), tx1);
                float cyp = fminf(fmaxf(cu.y, ty0), ty1);
                float ddx = cu.x - cxp, ddy = cu.y - cyp;
                ov = (ddx*ddx + ddy*ddy) <= cu.z;
                if (ov) { a4 = gA[g]; b4 = gB[g]; }
            }
            unsigned long long mm = __ballot(ov);
            while (mm) {
                int l = __ffsll(mm) - 1;
                mm &= mm - 1ull;
                float su0 = __shfl(cu.x, l), su1 = __shfl(cu.y, l);
                float ci0 = __shfl(a4.x, l), ci1 = __shfl(a4.y, l);
                float ci2 = __shfl(a4.z, l), sal = __shfl(a4.w, l);
                float cr  = __shfl(b4.x, l), cg  = __shfl(b4.y, l);
                float cbv = __shfl(b4.z, l);
                float ddx = pxf - su0, ddy = pyf - su1;
                float power = -0.5f*(ci0*ddx*ddx + ci2*ddy*ddy) - ci1*ddx*ddy;
                float alp = fminf(0.99f, sal * __expf(power));
                alp = (power <= 0.f && alp >= (1.0f/255.0f)) ? alp : 0.f;
                float w = (T > 0.0001f) ? alp * T : 0.f;
                aR = fmaf(w, cr, aR);
                aG = fmaf(w, cg, aG);
                aB = fmaf(w, cbv, aB);
                T = T - T * alp;
            }
            if (__all(T <= 0.0001f)) break;
        }
    }

    if (inb) {
        int pix = iy * W + ix;
        segbuf[(size_t)seg * (size_t)(W*H) + pix] = make_float4(T, aR, aG, aB);
    }
}

// ---------------------------------------------------------------------------
// Kernel 5: combine depth segments front-to-back.
// ---------------------------------------------------------------------------
__global__ __launch_bounds__(256) void k_combine(
    const float4* __restrict__ segbuf, int HW, int nseg,
    float* __restrict__ out)
{
    int p = blockIdx.x * 256 + threadIdx.x;
    if (p >= HW) return;
    float T = 1.f, r = 0.f, g = 0.f, b = 0.f;
    for (int s = 0; s < nseg; ++s) {
        float4 v = segbuf[(size_t)s * HW + p];
        r = fmaf(T, v.y, r);
        g = fmaf(T, v.z, g);
        b = fmaf(T, v.w, b);
        T *= v.x;
    }
    out[p] = r; out[HW + p] = g; out[2*HW + p] = b;
}

// ---------------------------------------------------------------------------
extern "C" void kernel_launch(void* const* d_in, const int* in_sizes, int n_in,
                              void* d_out, int out_size, void* d_ws, size_t ws_size,
                              hipStream_t stream) {
    const float* pws        = (const float*)d_in[0];
    const float* shs        = (const float*)d_in[1];
    const float* alphas_raw = (const float*)d_in[2];
    const float* scales_raw = (const float*)d_in[3];
    const float* rots_raw   = (const float*)d_in[4];
    // d_in[5] = us (forward value cancels: u + us - us)
    const float* Rcw        = (const float*)d_in[6];
    const float* tcw        = (const float*)d_in[7];
    const float* intr       = (const float*)d_in[8];

    const int N  = in_sizes[0] / 3;
    const int HW = (out_size - 2 * N) / 3;
    int W = 1; while ((long long)W * W < (long long)HW) ++W;  // square image
    const int H = HW / W;

    float* out   = (float*)d_out;
    float* areas = out + 3 * HW;

    const int nseg = 8;
    int tilesX = (W + 7) / 8, tilesY = (H + 7) / 8;
    int nTiles = tilesX * tilesY;
    int nCnt = nTiles * nseg;

    // workspace carve-up (16B-aligned pieces)
    char* ws = (char*)d_ws;
    size_t off = 0;
    unsigned long long* keys = (unsigned long long*)(ws + off); off += (size_t)N * 8;
    unsigned* rank = (unsigned*)(ws + off);                     off += (size_t)N * 4;
    off = (off + 15) & ~(size_t)15;
    float* Pun = (float*)(ws + off);                            off += (size_t)10 * N * 4;
    off = (off + 15) & ~(size_t)15;
    float4* cullv = (float4*)(ws + off);                        off += (size_t)N * 16;
    float4* gA = (float4*)(ws + off);                           off += (size_t)N * 16;
    float4* gB = (float4*)(ws + off);                           off += (size_t)N * 16;
    unsigned* cnts = (unsigned*)(ws + off);                     off += (size_t)(nCnt + 1) * 4;
    unsigned* bigCnt = cnts + nCnt;   // zeroed together with cnts in k_pre
    off = (off + 15) & ~(size_t)15;
    int* blist = (int*)(ws + off);                              off += (size_t)nCnt * BCAP * 4;
    int* bigList = (int*)(ws + off);                            off += (size_t)N * 4;
    off = (off + 15) & ~(size_t)15;
    float4* segbuf = (float4*)(ws + off);

    k_pre<<<(N + 63) / 64, 64, 0, stream>>>(pws, shs, alphas_raw, scales_raw,
                                            rots_raw, Rcw, tcw, intr, N, W, H,
                                            areas, keys, rank, Pun, cnts, nCnt + 1);
    dim3 rgrid((N + 255) / 256, (N + JC - 1) / JC);
    k_rank_scatter<<<rgrid, 256, 0, stream>>>(keys, N, rank, Pun, gA, gB, cullv);
    k_bin<<<(N + 255) / 256, 256, 0, stream>>>(cullv, N, tilesX, tilesY, nseg,
                                               W, H, cnts, blist, bigList, bigCnt);
    k_bin_big<<<64, 256, 0, stream>>>(cullv, N, bigList, bigCnt, tilesX, tilesY,
                                      nseg, W, H, cnts, blist);
    k_render<<<nTiles * nseg, 64, 0, stream>>>(gA, gB, cullv, cnts, blist,
                                               N, W, H, nTiles, nseg, segbuf);
    k_combine<<<(HW + 255) / 256, 256, 0, stream>>>(segbuf, HW, nseg, out);
}

// Round 10
// 130.506 us; speedup vs baseline: 1.2140x; 1.2140x over previous
//
#include <hip/hip_runtime.h>

// ---------------------------------------------------------------------------
// Kernel 1: per-Gaussian preprocessing. 64-thread blocks. Writes areas,
// unsorted param SoA, depth sort keys, zero-inits rank + bin counters + nBig.
// ---------------------------------------------------------------------------
__global__ __launch_bounds__(64) void k_pre(
    const float* __restrict__ pws, const float* __restrict__ shs,
    const float* __restrict__ alphas_raw, const float* __restrict__ scales_raw,
    const float* __restrict__ rots_raw, const float* __restrict__ Rcw,
    const float* __restrict__ tcw, const float* __restrict__ intr,
    int N, int W, int H, float* __restrict__ areas,
    unsigned long long* __restrict__ keys, unsigned* __restrict__ rank,
    float* __restrict__ P, unsigned* __restrict__ cnts, int nCntTot)
{
    int i = blockIdx.x * 64 + threadIdx.x;
    if (i >= N) return;
    rank[i] = 0u;
    for (int z = i; z < nCntTot; z += N) cnts[z] = 0u;

    float R00=Rcw[0],R01=Rcw[1],R02=Rcw[2];
    float R10=Rcw[3],R11=Rcw[4],R12=Rcw[5];
    float R20=Rcw[6],R21=Rcw[7],R22=Rcw[8];
    float t0=tcw[0],t1=tcw[1],t2=tcw[2];
    float fx=intr[0],fy=intr[1],cx=intr[2],cy=intr[3];

    float pwx=pws[i*3+0], pwy=pws[i*3+1], pwz=pws[i*3+2];
    float pcx = R00*pwx + R01*pwy + R02*pwz + t0;
    float pcy = R10*pwx + R11*pwy + R12*pwz + t1;
    float pcz = R20*pwx + R21*pwy + R22*pwz + t2;
    float depth = pcz;
    float zs = (depth > 0.2f) ? depth : 1.0f;
    float u0 = fx * pcx / zs + cx;
    float u1 = fy * pcy / zs + cy;

    float4 q4 = *reinterpret_cast<const float4*>(rots_raw + i*4);
    float qw=q4.x, qx=q4.y, qy=q4.z, qz=q4.w;
    float qn = sqrtf(qw*qw + qx*qx + qy*qy + qz*qz);
    qw/=qn; qx/=qn; qy/=qn; qz/=qn;
    float s0 = expf(scales_raw[i*3+0]);
    float s1 = expf(scales_raw[i*3+1]);
    float s2 = expf(scales_raw[i*3+2]);

    float xx=qx*qx, yy=qy*qy, zq=qz*qz;
    float xy=qx*qy, xz=qx*qz, yz=qy*qz;
    float wx=qw*qx, wy=qw*qy, wz=qw*qz;
    float r00=1.f-2.f*(yy+zq), r01=2.f*(xy-wz),     r02=2.f*(xz+wy);
    float r10=2.f*(xy+wz),     r11=1.f-2.f*(xx+zq), r12=2.f*(yz-wx);
    float r20=2.f*(xz-wy),     r21=2.f*(yz+wx),     r22=1.f-2.f*(xx+yy);

    float m00=r00*s0, m01=r01*s1, m02=r02*s2;
    float m10=r10*s0, m11=r11*s1, m12=r12*s2;
    float m20=r20*s0, m21=r21*s1, m22=r22*s2;
    float V00=m00*m00+m01*m01+m02*m02;
    float V01=m00*m10+m01*m11+m02*m12;
    float V02=m00*m20+m01*m21+m02*m22;
    float V11=m10*m10+m11*m11+m12*m12;
    float V12=m10*m20+m11*m21+m12*m22;
    float V22=m20*m20+m21*m21+m22*m22;

    float tanfx = (float)W / (2.f*fx), tanfy = (float)H / (2.f*fy);
    float limx = 1.3f*tanfx, limy = 1.3f*tanfy;
    float txl = fminf(fmaxf(pcx/zs, -limx), limx) * zs;
    float tyl = fminf(fmaxf(pcy/zs, -limy), limy) * zs;
    float iz = 1.f/zs, iz2 = iz*iz;
    float J00 = fx*iz, J02 = -fx*txl*iz2;
    float J11 = fy*iz, J12 = -fy*tyl*iz2;

    float T00=J00*R00+J02*R20, T01=J00*R01+J02*R21, T02=J00*R02+J02*R22;
    float T10=J11*R10+J12*R20, T11=J11*R11+J12*R21, T12=J11*R12+J12*R22;
    float A0=T00*V00+T01*V01+T02*V02;
    float A1=T00*V01+T01*V11+T02*V12;
    float A2=T00*V02+T01*V12+T02*V22;
    float B0=T10*V00+T11*V01+T12*V02;
    float B1=T10*V01+T11*V11+T12*V12;
    float B2=T10*V02+T11*V12+T12*V22;
    float ca = A0*T00+A1*T01+A2*T02 + 0.3f;
    float cb = A0*T10+A1*T11+A2*T12;
    float cc = B0*T10+B1*T11+B2*T12 + 0.3f;

    float det = ca*cc - cb*cb;
    bool valid = (depth > 0.2f) && (det > 0.f);
    float det_s = valid ? det : 1.f;
    float dinv = 1.f/det_s;
    float ci0 =  cc*dinv, ci1 = -cb*dinv, ci2 = ca*dinv;
    float mid = 0.5f*(ca+cc);
    float lam = mid + sqrtf(fmaxf(mid*mid - det, 0.1f));
    float radius = valid ? ceilf(3.f*sqrtf(lam)) : 0.f;
    areas[2*i+0] = radius;
    areas[2*i+1] = radius;

    float alpha = 1.f/(1.f + expf(-alphas_raw[i]));

    float tw0 = -(R00*t0 + R10*t1 + R20*t2);
    float tw1 = -(R01*t0 + R11*t1 + R21*t2);
    float tw2 = -(R02*t0 + R12*t1 + R22*t2);
    float dx_=pwx-tw0, dy_=pwy-tw1, dz_=pwz-tw2;
    float dn = sqrtf(dx_*dx_+dy_*dy_+dz_*dz_);
    float x=dx_/dn, y=dy_/dn, z=dz_/dn;
    float sxx=x*x, syy=y*y, szz=z*z;
    float sxy=x*y, syz=y*z, sxz=x*z;

    float shl[48];
    const float4* sh4 = reinterpret_cast<const float4*>(shs + i*48);
    #pragma unroll
    for (int k = 0; k < 12; ++k) {
        float4 v = sh4[k];
        shl[4*k+0]=v.x; shl[4*k+1]=v.y; shl[4*k+2]=v.z; shl[4*k+3]=v.w;
    }
    float col[3];
    #pragma unroll
    for (int c = 0; c < 3; ++c) {
        float res = 0.28209479177387814f*shl[0*3+c];
        res += -0.4886025119029199f*y*shl[1*3+c]
             +  0.4886025119029199f*z*shl[2*3+c]
             + -0.4886025119029199f*x*shl[3*3+c];
        res +=  1.0925484305920792f*sxy*shl[4*3+c]
             + -1.0925484305920792f*syz*shl[5*3+c]
             +  0.31539156525252005f*(2.f*szz-sxx-syy)*shl[6*3+c]
             + -1.0925484305920792f*sxz*shl[7*3+c]
             +  0.5462742152960396f*(sxx-syy)*shl[8*3+c];
        res += -0.5900435899266435f*y*(3.f*sxx-syy)*shl[9*3+c]
             +  2.890611442640554f*sxy*z*shl[10*3+c]
             + -0.4570457994644658f*y*(4.f*szz-sxx-syy)*shl[11*3+c]
             +  0.3731763325901154f*z*(2.f*szz-3.f*sxx-3.f*syy)*shl[12*3+c]
             + -0.4570457994644658f*x*(4.f*szz-sxx-syy)*shl[13*3+c]
             +  1.445305721320277f*z*(sxx-syy)*shl[14*3+c]
             + -0.5900435899266435f*x*(sxx-3.f*syy)*shl[15*3+c];
        col[c] = fmaxf(res + 0.5f, 0.f);
    }

    float rc2;
    if (!valid || 255.f*alpha < 0.999f) {
        rc2 = -1.f;
    } else {
        float r2 = 2.f*lam*logf(255.f*alpha);
        float r  = sqrtf(fmaxf(r2, 0.f)) + 1.f;
        rc2 = r*r;
    }

    P[0*N+i]=u0;  P[1*N+i]=u1;  P[2*N+i]=ci0; P[3*N+i]=ci1; P[4*N+i]=ci2;
    P[5*N+i]=alpha; P[6*N+i]=col[0]; P[7*N+i]=col[1]; P[8*N+i]=col[2];
    P[9*N+i]=rc2;

    unsigned ud = __float_as_uint(depth);
    ud = (ud & 0x80000000u) ? ~ud : (ud | 0x80000000u);
    keys[i] = ((unsigned long long)ud << 32) | (unsigned)i;
}

// ---------------------------------------------------------------------------
// Kernel 2: O(N^2) rank sort fused with scatter ONLY (r6 form).
// ---------------------------------------------------------------------------
#define JC 512
#define BCAP 64
__global__ __launch_bounds__(256) void k_rank_scatter(
    const unsigned long long* __restrict__ keys, int N,
    unsigned* __restrict__ rank, const float* __restrict__ Pun,
    float4* __restrict__ gA, float4* __restrict__ gB,
    float4* __restrict__ cull)
{
    __shared__ unsigned long long sk[JC];
    const int j0 = blockIdx.y * JC;
    const int nJ = gridDim.y;
    for (int t = threadIdx.x; t < JC; t += 256) {
        int j = j0 + t;
        sk[t] = (j < N) ? keys[j] : ~0ull;
    }
    __syncthreads();

    const int i = blockIdx.x * 256 + threadIdx.x;
    unsigned long long my = (i < N) ? keys[i] : 0ull;

    int c = 0;
    const ulonglong2* sk2 = (const ulonglong2*)sk;
    #pragma unroll 4
    for (int t = 0; t < JC/2; ++t) {
        ulonglong2 kk = sk2[t];
        c += (kk.x < my) ? 1 : 0;
        c += (kk.y < my) ? 1 : 0;
    }
    if (i < N) {
        unsigned old = atomicAdd(&rank[i], (unsigned)c + (1u << 20));
        if ((int)(old >> 20) == nJ - 1) {
            int s = (int)(old & 0xFFFFFu) + c;
            cull[s] = make_float4(Pun[0*N+i], Pun[1*N+i], Pun[9*N+i], 0.f);
            gA[s]   = make_float4(Pun[2*N+i], Pun[3*N+i], Pun[4*N+i], Pun[5*N+i]);
            gB[s]   = make_float4(Pun[6*N+i], Pun[7*N+i], Pun[8*N+i], 0.f);
        }
    }
}

// ---------------------------------------------------------------------------
// Kernel 3: binning from the SORTED cull array. r9 lesson: typical footprint
// is 12-16 tiles (scale exp(-3), r~11px), so SMALLT=8 sent ~ALL splats to the
// big path and serialized there. SMALLT=32 keeps the typical splat in the
// per-thread path (<=32 address-independent return-atomics, pipelined across
// 8192 threads); only true near-camera monsters (>32 tiles) go to bigList.
// ---------------------------------------------------------------------------
#define SMALLT 32
__global__ __launch_bounds__(256) void k_bin(
    const float4* __restrict__ cull, int N,
    int tilesX, int tilesY, int nseg, int W, int H,
    unsigned* __restrict__ cnts, int* __restrict__ list,
    int* __restrict__ bigList, unsigned* __restrict__ bigCnt)
{
    int s = blockIdx.x * 256 + threadIdx.x;
    if (s >= N) return;
    float4 cu = cull[s];
    float u0 = cu.x, u1 = cu.y, rc2 = cu.z;
    if (rc2 <= 0.f) return;

    const int per = (N + nseg - 1) / nseg;
    const int seg = s / per;
    float rr = sqrtf(rc2);
    int x0 = (int)fminf(fmaxf(floorf((u0 - rr) * 0.125f), 0.f), (float)(tilesX - 1));
    int x1 = (int)fminf(fmaxf(floorf((u0 + rr) * 0.125f), 0.f), (float)(tilesX - 1));
    int y0 = (int)fminf(fmaxf(floorf((u1 - rr) * 0.125f), 0.f), (float)(tilesY - 1));
    int y1 = (int)fminf(fmaxf(floorf((u1 + rr) * 0.125f), 0.f), (float)(tilesY - 1));
    int tot = (x1 - x0 + 1) * (y1 - y0 + 1);

    if (tot > SMALLT) {
        unsigned p = atomicAdd(bigCnt, 1u);
        bigList[p] = s;            // capacity N: each splat appends at most once
        return;
    }
    for (int ty = y0; ty <= y1; ++ty) {
        float by0f = (float)(ty << 3);
        float by1f = fminf(by0f + 7.f, (float)(H - 1));
        float cyp  = fminf(fmaxf(u1, by0f), by1f);
        float ddy  = u1 - cyp;
        for (int tx = x0; tx <= x1; ++tx) {
            float bx0f = (float)(tx << 3);
            float bx1f = fminf(bx0f + 7.f, (float)(W - 1));
            float cxp  = fminf(fmaxf(u0, bx0f), bx1f);
            float ddx  = u0 - cxp;
            if (ddx*ddx + ddy*ddy <= rc2) {
                int lid = (ty * tilesX + tx) * nseg + seg;
                unsigned pos = atomicAdd(&cnts[lid], 1u);
                if (pos < (unsigned)BCAP) list[lid * BCAP + (int)pos] = s;
            }
        }
    }
}

// ---------------------------------------------------------------------------
// Kernel 3b: big-footprint splats (now only true monsters, nBig ~ 10-30).
// 512 blocks: each monster gets its own block (block-per-splat, strided),
// walking its bbox 256-wide. A 1024-tile monster = 4 atomics/thread.
// ---------------------------------------------------------------------------
__global__ __launch_bounds__(256) void k_bin_big(
    const float4* __restrict__ cull, int N,
    const int* __restrict__ bigList, const unsigned* __restrict__ bigCnt,
    int tilesX, int tilesY, int nseg, int W, int H,
    unsigned* __restrict__ cnts, int* __restrict__ list)
{
    const int nBig = (int)*bigCnt;
    const int per = (N + nseg - 1) / nseg;
    for (int b = blockIdx.x; b < nBig; b += gridDim.x) {
        int s = bigList[b];
        float4 cu = cull[s];
        float u0 = cu.x, u1 = cu.y, rc2 = cu.z;
        const int seg = s / per;
        float rr = sqrtf(rc2);
        int x0 = (int)fminf(fmaxf(floorf((u0 - rr) * 0.125f), 0.f), (float)(tilesX - 1));
        int x1 = (int)fminf(fmaxf(floorf((u0 + rr) * 0.125f), 0.f), (float)(tilesX - 1));
        int y0 = (int)fminf(fmaxf(floorf((u1 - rr) * 0.125f), 0.f), (float)(tilesY - 1));
        int y1 = (int)fminf(fmaxf(floorf((u1 + rr) * 0.125f), 0.f), (float)(tilesY - 1));
        int nx  = x1 - x0 + 1;
        int tot = nx * (y1 - y0 + 1);
        for (int t = threadIdx.x; t < tot; t += 256) {
            int tx = x0 + (t % nx);
            int ty = y0 + (t / nx);
            float by0f = (float)(ty << 3);
            float by1f = fminf(by0f + 7.f, (float)(H - 1));
            float cyp  = fminf(fmaxf(u1, by0f), by1f);
            float ddy  = u1 - cyp;
            float bx0f = (float)(tx << 3);
            float bx1f = fminf(bx0f + 7.f, (float)(W - 1));
            float cxp  = fminf(fmaxf(u0, bx0f), bx1f);
            float ddx  = u0 - cxp;
            if (ddx*ddx + ddy*ddy <= rc2) {
                int lid = (ty * tilesX + tx) * nseg + seg;
                unsigned pos = atomicAdd(&cnts[lid], 1u);
                if (pos < (unsigned)BCAP) list[lid * BCAP + (int)pos] = s;
            }
        }
    }
}

// ---------------------------------------------------------------------------
// Kernel 4: binned render (validated in r8/r9). One wave per (8x8 tile, seg).
// Bitonic sort restores depth order; shfl-broadcast composite; overflow
// (cnt > BCAP) falls back to full-segment scan.
// ---------------------------------------------------------------------------
__global__ __launch_bounds__(64) void k_render(
    const float4* __restrict__ gA, const float4* __restrict__ gB,
    const float4* __restrict__ cull, const unsigned* __restrict__ cnts,
    const int* __restrict__ list, int N, int W, int H,
    int nTiles, int nseg, float4* __restrict__ segbuf)
{
    const int lane = threadIdx.x;
    const int tilesX = (W + 7) >> 3;
    const int tile = blockIdx.x % nTiles, seg = blockIdx.x / nTiles;
    const int tX = tile % tilesX, tY = tile / tilesX;
    const int ix = (tX << 3) + (lane & 7);
    const int iy = (tY << 3) + (lane >> 3);
    const bool inb = (ix < W) && (iy < H);
    const float pxf = (float)ix, pyf = (float)iy;

    float T = inb ? 1.f : 0.f;
    float aR = 0.f, aG = 0.f, aB = 0.f;

    const int lid = tile * nseg + seg;
    int cnt = (int)cnts[lid];

    if (cnt <= BCAP) {
        int v = (lane < cnt) ? list[lid * BCAP + lane] : 0x7FFFFFFF;
        #pragma unroll
        for (int k = 2; k <= 64; k <<= 1) {
            #pragma unroll
            for (int j = k >> 1; j > 0; j >>= 1) {
                int other = __shfl_xor(v, j);
                bool up = ((lane & k) == 0);
                bool takeMax = (((lane & j) != 0) == up);
                v = takeMax ? max(v, other) : min(v, other);
            }
        }
        float4 cu = make_float4(0.f,0.f,0.f,0.f);
        float4 a4 = make_float4(0.f,0.f,0.f,0.f);
        float4 b4 = make_float4(0.f,0.f,0.f,0.f);
        if (lane < cnt) { cu = cull[v]; a4 = gA[v]; b4 = gB[v]; }
        for (int e = 0; e < cnt; ++e) {
            float su0 = __shfl(cu.x, e), su1 = __shfl(cu.y, e);
            float ci0 = __shfl(a4.x, e), ci1 = __shfl(a4.y, e);
            float ci2 = __shfl(a4.z, e), sal = __shfl(a4.w, e);
            float cr  = __shfl(b4.x, e), cg  = __shfl(b4.y, e);
            float cbv = __shfl(b4.z, e);
            float ddx = pxf - su0, ddy = pyf - su1;
            float power = -0.5f*(ci0*ddx*ddx + ci2*ddy*ddy) - ci1*ddx*ddy;
            float alp = fminf(0.99f, sal * __expf(power));
            alp = (power <= 0.f && alp >= (1.0f/255.0f)) ? alp : 0.f;
            float w = (T > 0.0001f) ? alp * T : 0.f;
            aR = fmaf(w, cr, aR);
            aG = fmaf(w, cg, aG);
            aB = fmaf(w, cbv, aB);
            T = T - T * alp;
        }
    } else {
        const float tx0 = (float)(tX << 3), ty0 = (float)(tY << 3);
        int tx1i = (tX << 3) + 7; if (tx1i > W-1) tx1i = W-1;
        int ty1i = (tY << 3) + 7; if (ty1i > H-1) ty1i = H-1;
        const float tx1 = (float)tx1i, ty1 = (float)ty1i;
        const int per = (N + nseg - 1) / nseg;
        const int g0 = seg * per;
        const int g1 = min(N, g0 + per);
        for (int base = g0; base < g1; base += 64) {
            int g = base + lane;
            bool ov = false;
            float4 cu = make_float4(0.f,0.f,0.f,0.f);
            float4 a4 = make_float4(0.f,0.f,0.f,0.f);
            float4 b4 = make_float4(0.f,0.f,0.f,0.f);
            if (g < g1) {
                cu = cull[g];
                float cxp = fminf(fmaxf(cu.x, tx0), tx1);
                float cyp = fminf(fmaxf(cu.y, ty0), ty1);
                float ddx = cu.x - cxp, ddy = cu.y - cyp;
                ov = (ddx*ddx + ddy*ddy) <= cu.z;
                if (ov) { a4 = gA[g]; b4 = gB[g]; }
            }
            unsigned long long mm = __ballot(ov);
            while (mm) {
                int l = __ffsll(mm) - 1;
                mm &= mm - 1ull;
                float su0 = __shfl(cu.x, l), su1 = __shfl(cu.y, l);
                float ci0 = __shfl(a4.x, l), ci1 = __shfl(a4.y, l);
                float ci2 = __shfl(a4.z, l), sal = __shfl(a4.w, l);
                float cr  = __shfl(b4.x, l), cg  = __shfl(b4.y, l);
                float cbv = __shfl(b4.z, l);
                float ddx = pxf - su0, ddy = pyf - su1;
                float power = -0.5f*(ci0*ddx*ddx + ci2*ddy*ddy) - ci1*ddx*ddy;
                float alp = fminf(0.99f, sal * __expf(power));
                alp = (power <= 0.f && alp >= (1.0f/255.0f)) ? alp : 0.f;
                float w = (T > 0.0001f) ? alp * T : 0.f;
                aR = fmaf(w, cr, aR);
                aG = fmaf(w, cg, aG);
                aB = fmaf(w, cbv, aB);
                T = T - T * alp;
            }
            if (__all(T <= 0.0001f)) break;
        }
    }

    if (inb) {
        int pix = iy * W + ix;
        segbuf[(size_t)seg * (size_t)(W*H) + pix] = make_float4(T, aR, aG, aB);
    }
}

// ---------------------------------------------------------------------------
// Kernel 5: combine depth segments front-to-back.
// ---------------------------------------------------------------------------
__global__ __launch_bounds__(256) void k_combine(
    const float4* __restrict__ segbuf, int HW, int nseg,
    float* __restrict__ out)
{
    int p = blockIdx.x * 256 + threadIdx.x;
    if (p >= HW) return;
    float T = 1.f, r = 0.f, g = 0.f, b = 0.f;
    for (int s = 0; s < nseg; ++s) {
        float4 v = segbuf[(size_t)s * HW + p];
        r = fmaf(T, v.y, r);
        g = fmaf(T, v.z, g);
        b = fmaf(T, v.w, b);
        T *= v.x;
    }
    out[p] = r; out[HW + p] = g; out[2*HW + p] = b;
}

// ---------------------------------------------------------------------------
extern "C" void kernel_launch(void* const* d_in, const int* in_sizes, int n_in,
                              void* d_out, int out_size, void* d_ws, size_t ws_size,
                              hipStream_t stream) {
    const float* pws        = (const float*)d_in[0];
    const float* shs        = (const float*)d_in[1];
    const float* alphas_raw = (const float*)d_in[2];
    const float* scales_raw = (const float*)d_in[3];
    const float* rots_raw   = (const float*)d_in[4];
    // d_in[5] = us (forward value cancels: u + us - us)
    const float* Rcw        = (const float*)d_in[6];
    const float* tcw        = (const float*)d_in[7];
    const float* intr       = (const float*)d_in[8];

    const int N  = in_sizes[0] / 3;
    const int HW = (out_size - 2 * N) / 3;
    int W = 1; while ((long long)W * W < (long long)HW) ++W;  // square image
    const int H = HW / W;

    float* out   = (float*)d_out;
    float* areas = out + 3 * HW;

    const int nseg = 8;
    int tilesX = (W + 7) / 8, tilesY = (H + 7) / 8;
    int nTiles = tilesX * tilesY;
    int nCnt = nTiles * nseg;

    // workspace carve-up (16B-aligned pieces)
    char* ws = (char*)d_ws;
    size_t off = 0;
    unsigned long long* keys = (unsigned long long*)(ws + off); off += (size_t)N * 8;
    unsigned* rank = (unsigned*)(ws + off);                     off += (size_t)N * 4;
    off = (off + 15) & ~(size_t)15;
    float* Pun = (float*)(ws + off);                            off += (size_t)10 * N * 4;
    off = (off + 15) & ~(size_t)15;
    float4* cullv = (float4*)(ws + off);                        off += (size_t)N * 16;
    float4* gA = (float4*)(ws + off);                           off += (size_t)N * 16;
    float4* gB = (float4*)(ws + off);                           off += (size_t)N * 16;
    unsigned* cnts = (unsigned*)(ws + off);                     off += (size_t)(nCnt + 1) * 4;
    unsigned* bigCnt = cnts + nCnt;   // zeroed together with cnts in k_pre
    off = (off + 15) & ~(size_t)15;
    int* blist = (int*)(ws + off);                              off += (size_t)nCnt * BCAP * 4;
    int* bigList = (int*)(ws + off);                            off += (size_t)N * 4;
    off = (off + 15) & ~(size_t)15;
    float4* segbuf = (float4*)(ws + off);

    k_pre<<<(N + 63) / 64, 64, 0, stream>>>(pws, shs, alphas_raw, scales_raw,
                                            rots_raw, Rcw, tcw, intr, N, W, H,
                                            areas, keys, rank, Pun, cnts, nCnt + 1);
    dim3 rgrid((N + 255) / 256, (N + JC - 1) / JC);
    k_rank_scatter<<<rgrid, 256, 0, stream>>>(keys, N, rank, Pun, gA, gB, cullv);
    k_bin<<<(N + 255) / 256, 256, 0, stream>>>(cullv, N, tilesX, tilesY, nseg,
                                               W, H, cnts, blist, bigList, bigCnt);
    k_bin_big<<<512, 256, 0, stream>>>(cullv, N, bigList, bigCnt, tilesX, tilesY,
                                       nseg, W, H, cnts, blist);
    k_render<<<nTiles * nseg, 64, 0, stream>>>(gA, gB, cullv, cnts, blist,
                                               N, W, H, nTiles, nseg, segbuf);
    k_combine<<<(HW + 255) / 256, 256, 0, stream>>>(segbuf, HW, nseg, out);
}

// Round 11
// 116.140 us; speedup vs baseline: 1.3642x; 1.1237x over previous
//
#include <hip/hip_runtime.h>

// ---------------------------------------------------------------------------
// Kernel 1: per-Gaussian preprocessing. 64-thread blocks. Writes areas,
// unsorted param SoA, depth sort keys, zero-inits rank + bin counters + nBig.
// ---------------------------------------------------------------------------
__global__ __launch_bounds__(64) void k_pre(
    const float* __restrict__ pws, const float* __restrict__ shs,
    const float* __restrict__ alphas_raw, const float* __restrict__ scales_raw,
    const float* __restrict__ rots_raw, const float* __restrict__ Rcw,
    const float* __restrict__ tcw, const float* __restrict__ intr,
    int N, int W, int H, float* __restrict__ areas,
    unsigned long long* __restrict__ keys, unsigned* __restrict__ rank,
    float* __restrict__ P, unsigned* __restrict__ cnts, int nCntTot)
{
    int i = blockIdx.x * 64 + threadIdx.x;
    if (i >= N) return;
    rank[i] = 0u;
    for (int z = i; z < nCntTot; z += N) cnts[z] = 0u;

    float R00=Rcw[0],R01=Rcw[1],R02=Rcw[2];
    float R10=Rcw[3],R11=Rcw[4],R12=Rcw[5];
    float R20=Rcw[6],R21=Rcw[7],R22=Rcw[8];
    float t0=tcw[0],t1=tcw[1],t2=tcw[2];
    float fx=intr[0],fy=intr[1],cx=intr[2],cy=intr[3];

    float pwx=pws[i*3+0], pwy=pws[i*3+1], pwz=pws[i*3+2];
    float pcx = R00*pwx + R01*pwy + R02*pwz + t0;
    float pcy = R10*pwx + R11*pwy + R12*pwz + t1;
    float pcz = R20*pwx + R21*pwy + R22*pwz + t2;
    float depth = pcz;
    float zs = (depth > 0.2f) ? depth : 1.0f;
    float u0 = fx * pcx / zs + cx;
    float u1 = fy * pcy / zs + cy;

    float4 q4 = *reinterpret_cast<const float4*>(rots_raw + i*4);
    float qw=q4.x, qx=q4.y, qy=q4.z, qz=q4.w;
    float qn = sqrtf(qw*qw + qx*qx + qy*qy + qz*qz);
    qw/=qn; qx/=qn; qy/=qn; qz/=qn;
    float s0 = expf(scales_raw[i*3+0]);
    float s1 = expf(scales_raw[i*3+1]);
    float s2 = expf(scales_raw[i*3+2]);

    float xx=qx*qx, yy=qy*qy, zq=qz*qz;
    float xy=qx*qy, xz=qx*qz, yz=qy*qz;
    float wx=qw*qx, wy=qw*qy, wz=qw*qz;
    float r00=1.f-2.f*(yy+zq), r01=2.f*(xy-wz),     r02=2.f*(xz+wy);
    float r10=2.f*(xy+wz),     r11=1.f-2.f*(xx+zq), r12=2.f*(yz-wx);
    float r20=2.f*(xz-wy),     r21=2.f*(yz+wx),     r22=1.f-2.f*(xx+yy);

    float m00=r00*s0, m01=r01*s1, m02=r02*s2;
    float m10=r10*s0, m11=r11*s1, m12=r12*s2;
    float m20=r20*s0, m21=r21*s1, m22=r22*s2;
    float V00=m00*m00+m01*m01+m02*m02;
    float V01=m00*m10+m01*m11+m02*m12;
    float V02=m00*m20+m01*m21+m02*m22;
    float V11=m10*m10+m11*m11+m12*m12;
    float V12=m10*m20+m11*m21+m12*m22;
    float V22=m20*m20+m21*m21+m22*m22;

    float tanfx = (float)W / (2.f*fx), tanfy = (float)H / (2.f*fy);
    float limx = 1.3f*tanfx, limy = 1.3f*tanfy;
    float txl = fminf(fmaxf(pcx/zs, -limx), limx) * zs;
    float tyl = fminf(fmaxf(pcy/zs, -limy), limy) * zs;
    float iz = 1.f/zs, iz2 = iz*iz;
    float J00 = fx*iz, J02 = -fx*txl*iz2;
    float J11 = fy*iz, J12 = -fy*tyl*iz2;

    float T00=J00*R00+J02*R20, T01=J00*R01+J02*R21, T02=J00*R02+J02*R22;
    float T10=J11*R10+J12*R20, T11=J11*R11+J12*R21, T12=J11*R12+J12*R22;
    float A0=T00*V00+T01*V01+T02*V02;
    float A1=T00*V01+T01*V11+T02*V12;
    float A2=T00*V02+T01*V12+T02*V22;
    float B0=T10*V00+T11*V01+T12*V02;
    float B1=T10*V01+T11*V11+T12*V12;
    float B2=T10*V02+T11*V12+T12*V22;
    float ca = A0*T00+A1*T01+A2*T02 + 0.3f;
    float cb = A0*T10+A1*T11+A2*T12;
    float cc = B0*T10+B1*T11+B2*T12 + 0.3f;

    float det = ca*cc - cb*cb;
    bool valid = (depth > 0.2f) && (det > 0.f);
    float det_s = valid ? det : 1.f;
    float dinv = 1.f/det_s;
    float ci0 =  cc*dinv, ci1 = -cb*dinv, ci2 = ca*dinv;
    float mid = 0.5f*(ca+cc);
    float lam = mid + sqrtf(fmaxf(mid*mid - det, 0.1f));
    float radius = valid ? ceilf(3.f*sqrtf(lam)) : 0.f;
    areas[2*i+0] = radius;
    areas[2*i+1] = radius;

    float alpha = 1.f/(1.f + expf(-alphas_raw[i]));

    float tw0 = -(R00*t0 + R10*t1 + R20*t2);
    float tw1 = -(R01*t0 + R11*t1 + R21*t2);
    float tw2 = -(R02*t0 + R12*t1 + R22*t2);
    float dx_=pwx-tw0, dy_=pwy-tw1, dz_=pwz-tw2;
    float dn = sqrtf(dx_*dx_+dy_*dy_+dz_*dz_);
    float x=dx_/dn, y=dy_/dn, z=dz_/dn;
    float sxx=x*x, syy=y*y, szz=z*z;
    float sxy=x*y, syz=y*z, sxz=x*z;

    float shl[48];
    const float4* sh4 = reinterpret_cast<const float4*>(shs + i*48);
    #pragma unroll
    for (int k = 0; k < 12; ++k) {
        float4 v = sh4[k];
        shl[4*k+0]=v.x; shl[4*k+1]=v.y; shl[4*k+2]=v.z; shl[4*k+3]=v.w;
    }
    float col[3];
    #pragma unroll
    for (int c = 0; c < 3; ++c) {
        float res = 0.28209479177387814f*shl[0*3+c];
        res += -0.4886025119029199f*y*shl[1*3+c]
             +  0.4886025119029199f*z*shl[2*3+c]
             + -0.4886025119029199f*x*shl[3*3+c];
        res +=  1.0925484305920792f*sxy*shl[4*3+c]
             + -1.0925484305920792f*syz*shl[5*3+c]
             +  0.31539156525252005f*(2.f*szz-sxx-syy)*shl[6*3+c]
             + -1.0925484305920792f*sxz*shl[7*3+c]
             +  0.5462742152960396f*(sxx-syy)*shl[8*3+c];
        res += -0.5900435899266435f*y*(3.f*sxx-syy)*shl[9*3+c]
             +  2.890611442640554f*sxy*z*shl[10*3+c]
             + -0.4570457994644658f*y*(4.f*szz-sxx-syy)*shl[11*3+c]
             +  0.3731763325901154f*z*(2.f*szz-3.f*sxx-3.f*syy)*shl[12*3+c]
             + -0.4570457994644658f*x*(4.f*szz-sxx-syy)*shl[13*3+c]
             +  1.445305721320277f*z*(sxx-syy)*shl[14*3+c]
             + -0.5900435899266435f*x*(sxx-3.f*syy)*shl[15*3+c];
        col[c] = fmaxf(res + 0.5f, 0.f);
    }

    float rc2;
    if (!valid || 255.f*alpha < 0.999f) {
        rc2 = -1.f;
    } else {
        float r2 = 2.f*lam*logf(255.f*alpha);
        float r  = sqrtf(fmaxf(r2, 0.f)) + 1.f;
        rc2 = r*r;
    }

    P[0*N+i]=u0;  P[1*N+i]=u1;  P[2*N+i]=ci0; P[3*N+i]=ci1; P[4*N+i]=ci2;
    P[5*N+i]=alpha; P[6*N+i]=col[0]; P[7*N+i]=col[1]; P[8*N+i]=col[2];
    P[9*N+i]=rc2;

    unsigned ud = __float_as_uint(depth);
    ud = (ud & 0x80000000u) ? ~ud : (ud | 0x80000000u);
    keys[i] = ((unsigned long long)ud << 32) | (unsigned)i;
}

// ---------------------------------------------------------------------------
// Kernel 2: O(N^2) rank sort fused with scatter ONLY (r6 form).
// ---------------------------------------------------------------------------
#define JC 512
#define BCAP 64
__global__ __launch_bounds__(256) void k_rank_scatter(
    const unsigned long long* __restrict__ keys, int N,
    unsigned* __restrict__ rank, const float* __restrict__ Pun,
    float4* __restrict__ gA, float4* __restrict__ gB,
    float4* __restrict__ cull)
{
    __shared__ unsigned long long sk[JC];
    const int j0 = blockIdx.y * JC;
    const int nJ = gridDim.y;
    for (int t = threadIdx.x; t < JC; t += 256) {
        int j = j0 + t;
        sk[t] = (j < N) ? keys[j] : ~0ull;
    }
    __syncthreads();

    const int i = blockIdx.x * 256 + threadIdx.x;
    unsigned long long my = (i < N) ? keys[i] : 0ull;

    int c = 0;
    const ulonglong2* sk2 = (const ulonglong2*)sk;
    #pragma unroll 4
    for (int t = 0; t < JC/2; ++t) {
        ulonglong2 kk = sk2[t];
        c += (kk.x < my) ? 1 : 0;
        c += (kk.y < my) ? 1 : 0;
    }
    if (i < N) {
        unsigned old = atomicAdd(&rank[i], (unsigned)c + (1u << 20));
        if ((int)(old >> 20) == nJ - 1) {
            int s = (int)(old & 0xFFFFFu) + c;
            cull[s] = make_float4(Pun[0*N+i], Pun[1*N+i], Pun[9*N+i], 0.f);
            gA[s]   = make_float4(Pun[2*N+i], Pun[3*N+i], Pun[4*N+i], Pun[5*N+i]);
            gB[s]   = make_float4(Pun[6*N+i], Pun[7*N+i], Pun[8*N+i], 0.f);
        }
    }
}

// ---------------------------------------------------------------------------
// Kernel 3: binning, FLATTENED: one thread per (splat, bbox-slot), 32 slots.
// r10 lesson: the per-thread serial tile walk put 8100 x ~12 dependent-atomic
// steps on 32 blocks (1/8 of the CUs) -> ~22us hidden cost. Now each thread
// does at most ONE tile test + ONE atomic; 262k threads over 1024 blocks.
// Slot 0 routes footprints >32 tiles to bigList for k_bin_big.
// ---------------------------------------------------------------------------
#define SMALLT 32
__global__ __launch_bounds__(256) void k_bin(
    const float4* __restrict__ cull, int N,
    int tilesX, int tilesY, int nseg, int W, int H,
    unsigned* __restrict__ cnts, int* __restrict__ list,
    int* __restrict__ bigList, unsigned* __restrict__ bigCnt)
{
    int idx  = blockIdx.x * 256 + threadIdx.x;
    int s    = idx >> 5;
    int slot = idx & 31;
    if (s >= N) return;
    float4 cu = cull[s];
    float u0 = cu.x, u1 = cu.y, rc2 = cu.z;
    if (rc2 <= 0.f) return;

    float rr = sqrtf(rc2);
    int x0 = (int)fminf(fmaxf(floorf((u0 - rr) * 0.125f), 0.f), (float)(tilesX - 1));
    int x1 = (int)fminf(fmaxf(floorf((u0 + rr) * 0.125f), 0.f), (float)(tilesX - 1));
    int y0 = (int)fminf(fmaxf(floorf((u1 - rr) * 0.125f), 0.f), (float)(tilesY - 1));
    int y1 = (int)fminf(fmaxf(floorf((u1 + rr) * 0.125f), 0.f), (float)(tilesY - 1));
    int nx  = x1 - x0 + 1;
    int tot = nx * (y1 - y0 + 1);

    if (tot > SMALLT) {
        if (slot == 0) {
            unsigned p = atomicAdd(bigCnt, 1u);
            bigList[p] = s;        // capacity N: each splat appends at most once
        }
        return;
    }
    if (slot >= tot) return;

    int tx = x0 + (slot % nx);
    int ty = y0 + (slot / nx);
    float by0f = (float)(ty << 3);
    float by1f = fminf(by0f + 7.f, (float)(H - 1));
    float cyp  = fminf(fmaxf(u1, by0f), by1f);
    float ddy  = u1 - cyp;
    float bx0f = (float)(tx << 3);
    float bx1f = fminf(bx0f + 7.f, (float)(W - 1));
    float cxp  = fminf(fmaxf(u0, bx0f), bx1f);
    float ddx  = u0 - cxp;
    if (ddx*ddx + ddy*ddy <= rc2) {
        const int per = (N + nseg - 1) / nseg;
        const int seg = s / per;
        int lid = (ty * tilesX + tx) * nseg + seg;
        unsigned pos = atomicAdd(&cnts[lid], 1u);
        if (pos < (unsigned)BCAP) list[lid * BCAP + (int)pos] = s;
    }
}

// ---------------------------------------------------------------------------
// Kernel 3b: big-footprint splats (true monsters only, nBig ~ 10-30).
// 512 blocks: block-per-splat, 256 threads stride the bbox tiles.
// ---------------------------------------------------------------------------
__global__ __launch_bounds__(256) void k_bin_big(
    const float4* __restrict__ cull, int N,
    const int* __restrict__ bigList, const unsigned* __restrict__ bigCnt,
    int tilesX, int tilesY, int nseg, int W, int H,
    unsigned* __restrict__ cnts, int* __restrict__ list)
{
    const int nBig = (int)*bigCnt;
    const int per = (N + nseg - 1) / nseg;
    for (int b = blockIdx.x; b < nBig; b += gridDim.x) {
        int s = bigList[b];
        float4 cu = cull[s];
        float u0 = cu.x, u1 = cu.y, rc2 = cu.z;
        const int seg = s / per;
        float rr = sqrtf(rc2);
        int x0 = (int)fminf(fmaxf(floorf((u0 - rr) * 0.125f), 0.f), (float)(tilesX - 1));
        int x1 = (int)fminf(fmaxf(floorf((u0 + rr) * 0.125f), 0.f), (float)(tilesX - 1));
        int y0 = (int)fminf(fmaxf(floorf((u1 - rr) * 0.125f), 0.f), (float)(tilesY - 1));
        int y1 = (int)fminf(fmaxf(floorf((u1 + rr) * 0.125f), 0.f), (float)(tilesY - 1));
        int nx  = x1 - x0 + 1;
        int tot = nx * (y1 - y0 + 1);
        for (int t = threadIdx.x; t < tot; t += 256) {
            int tx = x0 + (t % nx);
            int ty = y0 + (t / nx);
            float by0f = (float)(ty << 3);
            float by1f = fminf(by0f + 7.f, (float)(H - 1));
            float cyp  = fminf(fmaxf(u1, by0f), by1f);
            float ddy  = u1 - cyp;
            float bx0f = (float)(tx << 3);
            float bx1f = fminf(bx0f + 7.f, (float)(W - 1));
            float cxp  = fminf(fmaxf(u0, bx0f), bx1f);
            float ddx  = u0 - cxp;
            if (ddx*ddx + ddy*ddy <= rc2) {
                int lid = (ty * tilesX + tx) * nseg + seg;
                unsigned pos = atomicAdd(&cnts[lid], 1u);
                if (pos < (unsigned)BCAP) list[lid * BCAP + (int)pos] = s;
            }
        }
    }
}

// ---------------------------------------------------------------------------
// Kernel 4: binned render (validated r8-r10). One wave per (8x8 tile, seg).
// Bitonic sort restores depth order; shfl-broadcast composite; overflow
// (cnt > BCAP) falls back to full-segment scan.
// ---------------------------------------------------------------------------
__global__ __launch_bounds__(64) void k_render(
    const float4* __restrict__ gA, const float4* __restrict__ gB,
    const float4* __restrict__ cull, const unsigned* __restrict__ cnts,
    const int* __restrict__ list, int N, int W, int H,
    int nTiles, int nseg, float4* __restrict__ segbuf)
{
    const int lane = threadIdx.x;
    const int tilesX = (W + 7) >> 3;
    const int tile = blockIdx.x % nTiles, seg = blockIdx.x / nTiles;
    const int tX = tile % tilesX, tY = tile / tilesX;
    const int ix = (tX << 3) + (lane & 7);
    const int iy = (tY << 3) + (lane >> 3);
    const bool inb = (ix < W) && (iy < H);
    const float pxf = (float)ix, pyf = (float)iy;

    float T = inb ? 1.f : 0.f;
    float aR = 0.f, aG = 0.f, aB = 0.f;

    const int lid = tile * nseg + seg;
    int cnt = (int)cnts[lid];

    if (cnt <= BCAP) {
        int v = (lane < cnt) ? list[lid * BCAP + lane] : 0x7FFFFFFF;
        #pragma unroll
        for (int k = 2; k <= 64; k <<= 1) {
            #pragma unroll
            for (int j = k >> 1; j > 0; j >>= 1) {
                int other = __shfl_xor(v, j);
                bool up = ((lane & k) == 0);
                bool takeMax = (((lane & j) != 0) == up);
                v = takeMax ? max(v, other) : min(v, other);
            }
        }
        float4 cu = make_float4(0.f,0.f,0.f,0.f);
        float4 a4 = make_float4(0.f,0.f,0.f,0.f);
        float4 b4 = make_float4(0.f,0.f,0.f,0.f);
        if (lane < cnt) { cu = cull[v]; a4 = gA[v]; b4 = gB[v]; }
        for (int e = 0; e < cnt; ++e) {
            float su0 = __shfl(cu.x, e), su1 = __shfl(cu.y, e);
            float ci0 = __shfl(a4.x, e), ci1 = __shfl(a4.y, e);
            float ci2 = __shfl(a4.z, e), sal = __shfl(a4.w, e);
            float cr  = __shfl(b4.x, e), cg  = __shfl(b4.y, e);
            float cbv = __shfl(b4.z, e);
            float ddx = pxf - su0, ddy = pyf - su1;
            float power = -0.5f*(ci0*ddx*ddx + ci2*ddy*ddy) - ci1*ddx*ddy;
            float alp = fminf(0.99f, sal * __expf(power));
            alp = (power <= 0.f && alp >= (1.0f/255.0f)) ? alp : 0.f;
            float w = (T > 0.0001f) ? alp * T : 0.f;
            aR = fmaf(w, cr, aR);
            aG = fmaf(w, cg, aG);
            aB = fmaf(w, cbv, aB);
            T = T - T * alp;
        }
    } else {
        const float tx0 = (float)(tX << 3), ty0 = (float)(tY << 3);
        int tx1i = (tX << 3) + 7; if (tx1i > W-1) tx1i = W-1;
        int ty1i = (tY << 3) + 7; if (ty1i > H-1) ty1i = H-1;
        const float tx1 = (float)tx1i, ty1 = (float)ty1i;
        const int per = (N + nseg - 1) / nseg;
        const int g0 = seg * per;
        const int g1 = min(N, g0 + per);
        for (int base = g0; base < g1; base += 64) {
            int g = base + lane;
            bool ov = false;
            float4 cu = make_float4(0.f,0.f,0.f,0.f);
            float4 a4 = make_float4(0.f,0.f,0.f,0.f);
            float4 b4 = make_float4(0.f,0.f,0.f,0.f);
            if (g < g1) {
                cu = cull[g];
                float cxp = fminf(fmaxf(cu.x, tx0), tx1);
                float cyp = fminf(fmaxf(cu.y, ty0), ty1);
                float ddx = cu.x - cxp, ddy = cu.y - cyp;
                ov = (ddx*ddx + ddy*ddy) <= cu.z;
                if (ov) { a4 = gA[g]; b4 = gB[g]; }
            }
            unsigned long long mm = __ballot(ov);
            while (mm) {
                int l = __ffsll(mm) - 1;
                mm &= mm - 1ull;
                float su0 = __shfl(cu.x, l), su1 = __shfl(cu.y, l);
                float ci0 = __shfl(a4.x, l), ci1 = __shfl(a4.y, l);
                float ci2 = __shfl(a4.z, l), sal = __shfl(a4.w, l);
                float cr  = __shfl(b4.x, l), cg  = __shfl(b4.y, l);
                float cbv = __shfl(b4.z, l);
                float ddx = pxf - su0, ddy = pyf - su1;
                float power = -0.5f*(ci0*ddx*ddx + ci2*ddy*ddy) - ci1*ddx*ddy;
                float alp = fminf(0.99f, sal * __expf(power));
                alp = (power <= 0.f && alp >= (1.0f/255.0f)) ? alp : 0.f;
                float w = (T > 0.0001f) ? alp * T : 0.f;
                aR = fmaf(w, cr, aR);
                aG = fmaf(w, cg, aG);
                aB = fmaf(w, cbv, aB);
                T = T - T * alp;
            }
            if (__all(T <= 0.0001f)) break;
        }
    }

    if (inb) {
        int pix = iy * W + ix;
        segbuf[(size_t)seg * (size_t)(W*H) + pix] = make_float4(T, aR, aG, aB);
    }
}

// ---------------------------------------------------------------------------
// Kernel 5: combine depth segments front-to-back.
// ---------------------------------------------------------------------------
__global__ __launch_bounds__(256) void k_combine(
    const float4* __restrict__ segbuf, int HW, int nseg,
    float* __restrict__ out)
{
    int p = blockIdx.x * 256 + threadIdx.x;
    if (p >= HW) return;
    float T = 1.f, r = 0.f, g = 0.f, b = 0.f;
    for (int s = 0; s < nseg; ++s) {
        float4 v = segbuf[(size_t)s * HW + p];
        r = fmaf(T, v.y, r);
        g = fmaf(T, v.z, g);
        b = fmaf(T, v.w, b);
        T *= v.x;
    }
    out[p] = r; out[HW + p] = g; out[2*HW + p] = b;
}

// ---------------------------------------------------------------------------
extern "C" void kernel_launch(void* const* d_in, const int* in_sizes, int n_in,
                              void* d_out, int out_size, void* d_ws, size_t ws_size,
                              hipStream_t stream) {
    const float* pws        = (const float*)d_in[0];
    const float* shs        = (const float*)d_in[1];
    const float* alphas_raw = (const float*)d_in[2];
    const float* scales_raw = (const float*)d_in[3];
    const float* rots_raw   = (const float*)d_in[4];
    // d_in[5] = us (forward value cancels: u + us - us)
    const float* Rcw        = (const float*)d_in[6];
    const float* tcw        = (const float*)d_in[7];
    const float* intr       = (const float*)d_in[8];

    const int N  = in_sizes[0] / 3;
    const int HW = (out_size - 2 * N) / 3;
    int W = 1; while ((long long)W * W < (long long)HW) ++W;  // square image
    const int H = HW / W;

    float* out   = (float*)d_out;
    float* areas = out + 3 * HW;

    const int nseg = 8;
    int tilesX = (W + 7) / 8, tilesY = (H + 7) / 8;
    int nTiles = tilesX * tilesY;
    int nCnt = nTiles * nseg;

    // workspace carve-up (16B-aligned pieces)
    char* ws = (char*)d_ws;
    size_t off = 0;
    unsigned long long* keys = (unsigned long long*)(ws + off); off += (size_t)N * 8;
    unsigned* rank = (unsigned*)(ws + off);                     off += (size_t)N * 4;
    off = (off + 15) & ~(size_t)15;
    float* Pun = (float*)(ws + off);                            off += (size_t)10 * N * 4;
    off = (off + 15) & ~(size_t)15;
    float4* cullv = (float4*)(ws + off);                        off += (size_t)N * 16;
    float4* gA = (float4*)(ws + off);                           off += (size_t)N * 16;
    float4* gB = (float4*)(ws + off);                           off += (size_t)N * 16;
    unsigned* cnts = (unsigned*)(ws + off);                     off += (size_t)(nCnt + 1) * 4;
    unsigned* bigCnt = cnts + nCnt;   // zeroed together with cnts in k_pre
    off = (off + 15) & ~(size_t)15;
    int* blist = (int*)(ws + off);                              off += (size_t)nCnt * BCAP * 4;
    int* bigList = (int*)(ws + off);                            off += (size_t)N * 4;
    off = (off + 15) & ~(size_t)15;
    float4* segbuf = (float4*)(ws + off);

    k_pre<<<(N + 63) / 64, 64, 0, stream>>>(pws, shs, alphas_raw, scales_raw,
                                            rots_raw, Rcw, tcw, intr, N, W, H,
                                            areas, keys, rank, Pun, cnts, nCnt + 1);
    dim3 rgrid((N + 255) / 256, (N + JC - 1) / JC);
    k_rank_scatter<<<rgrid, 256, 0, stream>>>(keys, N, rank, Pun, gA, gB, cullv);
    k_bin<<<(N * 32 + 255) / 256, 256, 0, stream>>>(cullv, N, tilesX, tilesY,
                                                    nseg, W, H, cnts, blist,
                                                    bigList, bigCnt);
    k_bin_big<<<512, 256, 0, stream>>>(cullv, N, bigList, bigCnt, tilesX, tilesY,
                                       nseg, W, H, cnts, blist);
    k_render<<<nTiles * nseg, 64, 0, stream>>>(gA, gB, cullv, cnts, blist,
                                               N, W, H, nTiles, nseg, segbuf);
    k_combine<<<(HW + 255) / 256, 256, 0, stream>>>(segbuf, HW, nseg, out);
}

// Round 13
// 110.641 us; speedup vs baseline: 1.4320x; 1.0497x over previous
//
#include <hip/hip_runtime.h>

// ---------------------------------------------------------------------------
// Kernel 1: per-Gaussian preprocessing. 64-thread blocks. Writes areas,
// unsorted param SoA, depth sort keys, zero-inits rank.
// ---------------------------------------------------------------------------
__global__ __launch_bounds__(64) void k_pre(
    const float* __restrict__ pws, const float* __restrict__ shs,
    const float* __restrict__ alphas_raw, const float* __restrict__ scales_raw,
    const float* __restrict__ rots_raw, const float* __restrict__ Rcw,
    const float* __restrict__ tcw, const float* __restrict__ intr,
    int N, int W, int H, float* __restrict__ areas,
    unsigned long long* __restrict__ keys, unsigned* __restrict__ rank,
    float* __restrict__ P)
{
    int i = blockIdx.x * 64 + threadIdx.x;
    if (i >= N) return;
    rank[i] = 0u;

    float R00=Rcw[0],R01=Rcw[1],R02=Rcw[2];
    float R10=Rcw[3],R11=Rcw[4],R12=Rcw[5];
    float R20=Rcw[6],R21=Rcw[7],R22=Rcw[8];
    float t0=tcw[0],t1=tcw[1],t2=tcw[2];
    float fx=intr[0],fy=intr[1],cx=intr[2],cy=intr[3];

    float pwx=pws[i*3+0], pwy=pws[i*3+1], pwz=pws[i*3+2];
    float pcx = R00*pwx + R01*pwy + R02*pwz + t0;
    float pcy = R10*pwx + R11*pwy + R12*pwz + t1;
    float pcz = R20*pwx + R21*pwy + R22*pwz + t2;
    float depth = pcz;
    float zs = (depth > 0.2f) ? depth : 1.0f;
    float u0 = fx * pcx / zs + cx;
    float u1 = fy * pcy / zs + cy;

    float4 q4 = *reinterpret_cast<const float4*>(rots_raw + i*4);
    float qw=q4.x, qx=q4.y, qy=q4.z, qz=q4.w;
    float qn = sqrtf(qw*qw + qx*qx + qy*qy + qz*qz);
    qw/=qn; qx/=qn; qy/=qn; qz/=qn;
    float s0 = expf(scales_raw[i*3+0]);
    float s1 = expf(scales_raw[i*3+1]);
    float s2 = expf(scales_raw[i*3+2]);

    float xx=qx*qx, yy=qy*qy, zq=qz*qz;
    float xy=qx*qy, xz=qx*qz, yz=qy*qz;
    float wx=qw*qx, wy=qw*qy, wz=qw*qz;
    float r00=1.f-2.f*(yy+zq), r01=2.f*(xy-wz),     r02=2.f*(xz+wy);
    float r10=2.f*(xy+wz),     r11=1.f-2.f*(xx+zq), r12=2.f*(yz-wx);
    float r20=2.f*(xz-wy),     r21=2.f*(yz+wx),     r22=1.f-2.f*(xx+yy);

    float m00=r00*s0, m01=r01*s1, m02=r02*s2;
    float m10=r10*s0, m11=r11*s1, m12=r12*s2;
    float m20=r20*s0, m21=r21*s1, m22=r22*s2;
    float V00=m00*m00+m01*m01+m02*m02;
    float V01=m00*m10+m01*m11+m02*m12;
    float V02=m00*m20+m01*m21+m02*m22;
    float V11=m10*m10+m11*m11+m12*m12;
    float V12=m10*m20+m11*m21+m12*m22;
    float V22=m20*m20+m21*m21+m22*m22;

    float tanfx = (float)W / (2.f*fx), tanfy = (float)H / (2.f*fy);
    float limx = 1.3f*tanfx, limy = 1.3f*tanfy;
    float txl = fminf(fmaxf(pcx/zs, -limx), limx) * zs;
    float tyl = fminf(fmaxf(pcy/zs, -limy), limy) * zs;
    float iz = 1.f/zs, iz2 = iz*iz;
    float J00 = fx*iz, J02 = -fx*txl*iz2;
    float J11 = fy*iz, J12 = -fy*tyl*iz2;

    float T00=J00*R00+J02*R20, T01=J00*R01+J02*R21, T02=J00*R02+J02*R22;
    float T10=J11*R10+J12*R20, T11=J11*R11+J12*R21, T12=J11*R12+J12*R22;
    float A0=T00*V00+T01*V01+T02*V02;
    float A1=T00*V01+T01*V11+T02*V12;
    float A2=T00*V02+T01*V12+T02*V22;
    float B0=T10*V00+T11*V01+T12*V02;
    float B1=T10*V01+T11*V11+T12*V12;
    float B2=T10*V02+T11*V12+T12*V22;
    float ca = A0*T00+A1*T01+A2*T02 + 0.3f;
    float cb = A0*T10+A1*T11+A2*T12;
    float cc = B0*T10+B1*T11+B2*T12 + 0.3f;

    float det = ca*cc - cb*cb;
    bool valid = (depth > 0.2f) && (det > 0.f);
    float det_s = valid ? det : 1.f;
    float dinv = 1.f/det_s;
    float ci0 =  cc*dinv, ci1 = -cb*dinv, ci2 = ca*dinv;
    float mid = 0.5f*(ca+cc);
    float lam = mid + sqrtf(fmaxf(mid*mid - det, 0.1f));
    float radius = valid ? ceilf(3.f*sqrtf(lam)) : 0.f;
    areas[2*i+0] = radius;
    areas[2*i+1] = radius;

    float alpha = 1.f/(1.f + expf(-alphas_raw[i]));

    float tw0 = -(R00*t0 + R10*t1 + R20*t2);
    float tw1 = -(R01*t0 + R11*t1 + R21*t2);
    float tw2 = -(R02*t0 + R12*t1 + R22*t2);
    float dx_=pwx-tw0, dy_=pwy-tw1, dz_=pwz-tw2;
    float dn = sqrtf(dx_*dx_+dy_*dy_+dz_*dz_);
    float x=dx_/dn, y=dy_/dn, z=dz_/dn;
    float sxx=x*x, syy=y*y, szz=z*z;
    float sxy=x*y, syz=y*z, sxz=x*z;

    float shl[48];
    const float4* sh4 = reinterpret_cast<const float4*>(shs + i*48);
    #pragma unroll
    for (int k = 0; k < 12; ++k) {
        float4 v = sh4[k];
        shl[4*k+0]=v.x; shl[4*k+1]=v.y; shl[4*k+2]=v.z; shl[4*k+3]=v.w;
    }
    float col[3];
    #pragma unroll
    for (int c = 0; c < 3; ++c) {
        float res = 0.28209479177387814f*shl[0*3+c];
        res += -0.4886025119029199f*y*shl[1*3+c]
             +  0.4886025119029199f*z*shl[2*3+c]
             + -0.4886025119029199f*x*shl[3*3+c];
        res +=  1.0925484305920792f*sxy*shl[4*3+c]
             + -1.0925484305920792f*syz*shl[5*3+c]
             +  0.31539156525252005f*(2.f*szz-sxx-syy)*shl[6*3+c]
             + -1.0925484305920792f*sxz*shl[7*3+c]
             +  0.5462742152960396f*(sxx-syy)*shl[8*3+c];
        res += -0.5900435899266435f*y*(3.f*sxx-syy)*shl[9*3+c]
             +  2.890611442640554f*sxy*z*shl[10*3+c]
             + -0.4570457994644658f*y*(4.f*szz-sxx-syy)*shl[11*3+c]
             +  0.3731763325901154f*z*(2.f*szz-3.f*sxx-3.f*syy)*shl[12*3+c]
             + -0.4570457994644658f*x*(4.f*szz-sxx-syy)*shl[13*3+c]
             +  1.445305721320277f*z*(sxx-syy)*shl[14*3+c]
             + -0.5900435899266435f*x*(sxx-3.f*syy)*shl[15*3+c];
        col[c] = fmaxf(res + 0.5f, 0.f);
    }

    float rc2;
    if (!valid || 255.f*alpha < 0.999f) {
        rc2 = -1.f;
    } else {
        float r2 = 2.f*lam*logf(255.f*alpha);
        float r  = sqrtf(fmaxf(r2, 0.f)) + 1.f;
        rc2 = r*r;
    }

    P[0*N+i]=u0;  P[1*N+i]=u1;  P[2*N+i]=ci0; P[3*N+i]=ci1; P[4*N+i]=ci2;
    P[5*N+i]=alpha; P[6*N+i]=col[0]; P[7*N+i]=col[1]; P[8*N+i]=col[2];
    P[9*N+i]=rc2;

    unsigned ud = __float_as_uint(depth);
    ud = (ud & 0x80000000u) ? ~ud : (ud | 0x80000000u);
    keys[i] = ((unsigned long long)ud << 32) | (unsigned)i;
}

// ---------------------------------------------------------------------------
// Kernel 2: O(N^2) rank sort fused with scatter (r6 form, validated).
// ---------------------------------------------------------------------------
#define JC 512
__global__ __launch_bounds__(256) void k_rank_scatter(
    const unsigned long long* __restrict__ keys, int N,
    unsigned* __restrict__ rank, const float* __restrict__ Pun,
    float4* __restrict__ gA, float4* __restrict__ gB,
    float4* __restrict__ cull)
{
    __shared__ unsigned long long sk[JC];
    const int j0 = blockIdx.y * JC;
    const int nJ = gridDim.y;
    for (int t = threadIdx.x; t < JC; t += 256) {
        int j = j0 + t;
        sk[t] = (j < N) ? keys[j] : ~0ull;
    }
    __syncthreads();

    const int i = blockIdx.x * 256 + threadIdx.x;
    unsigned long long my = (i < N) ? keys[i] : 0ull;

    int c = 0;
    const ulonglong2* sk2 = (const ulonglong2*)sk;
    #pragma unroll 4
    for (int t = 0; t < JC/2; ++t) {
        ulonglong2 kk = sk2[t];
        c += (kk.x < my) ? 1 : 0;
        c += (kk.y < my) ? 1 : 0;
    }
    if (i < N) {
        unsigned old = atomicAdd(&rank[i], (unsigned)c + (1u << 20));
        if ((int)(old >> 20) == nJ - 1) {
            int s = (int)(old & 0xFFFFFu) + c;
            cull[s] = make_float4(Pun[0*N+i], Pun[1*N+i], Pun[9*N+i], 0.f);
            gA[s]   = make_float4(Pun[2*N+i], Pun[3*N+i], Pun[4*N+i], Pun[5*N+i]);
            gB[s]   = make_float4(Pun[6*N+i], Pun[7*N+i], Pun[8*N+i], 0.f);
        }
    }
}

// ---------------------------------------------------------------------------
// Kernel 3: scan render, r6 structure (shfl broadcast, no LDS, no barriers,
// 2-deep register prefetch) but 16x16 TILES with 4 PIXELS PER LANE (2x2 quad).
// Cull-test count = nTiles x N drops 4x (1024->256 tiles): the scan's
// issue-bound cost (r6: ~10M wave-instrs ~ 20us) becomes ~2.7M ~ 5-6us.
// Composite work per accepted splat covers 4 px/lane = same per-pixel cost.
// nseg=16 -> 4096 one-wave blocks = 16 WGs/CU (slot cap), 8-chunk chains.
// Local-T segmentation validated rounds 0/1/4/5/6/8-11.
// ---------------------------------------------------------------------------
__global__ __launch_bounds__(64) void k_render(
    const float4* __restrict__ gA, const float4* __restrict__ gB,
    const float4* __restrict__ cull, int N, int W, int H,
    int nTiles, int nseg, float4* __restrict__ segbuf)
{
    const int lane = threadIdx.x;
    const int tilesX = (W + 15) >> 4;
    const int tile = blockIdx.x % nTiles, seg = blockIdx.x / nTiles;
    const int tX = tile % tilesX, tY = tile / tilesX;
    const int bx = (tX << 4) + ((lane & 7) << 1);
    const int by = (tY << 4) + ((lane >> 3) << 1);

    float pxs[4], pys[4];
    bool  inb[4];
    #pragma unroll
    for (int q = 0; q < 4; ++q) {
        int qx = bx + (q & 1), qy = by + (q >> 1);
        pxs[q] = (float)qx; pys[q] = (float)qy;
        inb[q] = (qx < W) && (qy < H);
    }

    const float tx0 = (float)(tX << 4), ty0 = (float)(tY << 4);
    int tx1i = (tX << 4) + 15; if (tx1i > W-1) tx1i = W-1;
    int ty1i = (tY << 4) + 15; if (ty1i > H-1) ty1i = H-1;
    const float tx1 = (float)tx1i, ty1 = (float)ty1i;

    const int per = (N + nseg - 1) / nseg;
    const int g0 = seg * per;
    const int g1 = min(N, g0 + per);

    float T[4], aR[4], aG[4], aB[4];
    #pragma unroll
    for (int q = 0; q < 4; ++q) { T[q] = inb[q] ? 1.f : 0.f; aR[q]=aG[q]=aB[q]=0.f; }

    // prologue: chunk 0 into registers (clamped addr always valid; accept
    // still gated on true g < g1)
    int gl0 = min(g0 + lane, N - 1);
    float4 cu = cull[gl0];
    float4 a4 = gA[gl0];
    float4 b4 = gB[gl0];

    for (int base = g0; base < g1; base += 64) {
        // prefetch chunk k+1 (unconditional; consumed next iteration)
        float4 cu_n = make_float4(0.f, 0.f, -1.f, 0.f);
        float4 a4_n = make_float4(0.f, 0.f, 0.f, 0.f);
        float4 b4_n = make_float4(0.f, 0.f, 0.f, 0.f);
        if (base + 64 < g1) {
            int gln = min(base + 64 + lane, N - 1);
            cu_n = cull[gln];
            a4_n = gA[gln];
            b4_n = gB[gln];
        }

        // cull test vs 16x16 tile bbox (all data in regs)
        int g = base + lane;
        bool ov = false;
        if (g < g1) {
            float cxp = fminf(fmaxf(cu.x, tx0), tx1);
            float cyp = fminf(fmaxf(cu.y, ty0), ty1);
            float ddx = cu.x - cxp, ddy = cu.y - cyp;
            ov = (ddx*ddx + ddy*ddy) <= cu.z;
        }

        unsigned long long mm = __ballot(ov);
        while (mm) {
            int l = __ffsll(mm) - 1;
            mm &= mm - 1ull;
            float su0 = __shfl(cu.x, l), su1 = __shfl(cu.y, l);
            float ci0 = __shfl(a4.x, l), ci1 = __shfl(a4.y, l);
            float ci2 = __shfl(a4.z, l), sal = __shfl(a4.w, l);
            float cr  = __shfl(b4.x, l), cg  = __shfl(b4.y, l);
            float cbv = __shfl(b4.z, l);
            #pragma unroll
            for (int q = 0; q < 4; ++q) {
                float ddx = pxs[q] - su0, ddy = pys[q] - su1;
                float power = -0.5f*(ci0*ddx*ddx + ci2*ddy*ddy) - ci1*ddx*ddy;
                float alp = fminf(0.99f, sal * __expf(power));
                alp = (power <= 0.f && alp >= (1.0f/255.0f)) ? alp : 0.f;
                float w = (T[q] > 0.0001f) ? alp * T[q] : 0.f;
                aR[q] = fmaf(w, cr, aR[q]);
                aG[q] = fmaf(w, cg, aG[q]);
                aB[q] = fmaf(w, cbv, aB[q]);
                T[q] = T[q] - T[q] * alp;
            }
        }
        float Tm = fmaxf(fmaxf(T[0], T[1]), fmaxf(T[2], T[3]));
        if (__all(Tm <= 0.0001f)) break;
        cu = cu_n; a4 = a4_n; b4 = b4_n;
    }

    const size_t segBase = (size_t)seg * (size_t)(W * H);
    #pragma unroll
    for (int q = 0; q < 4; ++q) {
        if (inb[q]) {
            int pix = (by + (q >> 1)) * W + (bx + (q & 1));
            segbuf[segBase + pix] = make_float4(T[q], aR[q], aG[q], aB[q]);
        }
    }
}

// ---------------------------------------------------------------------------
// Kernel 4: combine depth segments front-to-back.
// ---------------------------------------------------------------------------
__global__ __launch_bounds__(256) void k_combine(
    const float4* __restrict__ segbuf, int HW, int nseg,
    float* __restrict__ out)
{
    int p = blockIdx.x * 256 + threadIdx.x;
    if (p >= HW) return;
    float T = 1.f, r = 0.f, g = 0.f, b = 0.f;
    for (int s = 0; s < nseg; ++s) {
        float4 v = segbuf[(size_t)s * HW + p];
        r = fmaf(T, v.y, r);
        g = fmaf(T, v.z, g);
        b = fmaf(T, v.w, b);
        T *= v.x;
    }
    out[p] = r; out[HW + p] = g; out[2*HW + p] = b;
}

// ---------------------------------------------------------------------------
extern "C" void kernel_launch(void* const* d_in, const int* in_sizes, int n_in,
                              void* d_out, int out_size, void* d_ws, size_t ws_size,
                              hipStream_t stream) {
    const float* pws        = (const float*)d_in[0];
    const float* shs        = (const float*)d_in[1];
    const float* alphas_raw = (const float*)d_in[2];
    const float* scales_raw = (const float*)d_in[3];
    const float* rots_raw   = (const float*)d_in[4];
    // d_in[5] = us (forward value cancels: u + us - us)
    const float* Rcw        = (const float*)d_in[6];
    const float* tcw        = (const float*)d_in[7];
    const float* intr       = (const float*)d_in[8];

    const int N  = in_sizes[0] / 3;
    const int HW = (out_size - 2 * N) / 3;
    int W = 1; while ((long long)W * W < (long long)HW) ++W;  // square image
    const int H = HW / W;

    float* out   = (float*)d_out;
    float* areas = out + 3 * HW;

    // workspace carve-up (16B-aligned pieces)
    char* ws = (char*)d_ws;
    size_t off = 0;
    unsigned long long* keys = (unsigned long long*)(ws + off); off += (size_t)N * 8;
    unsigned* rank = (unsigned*)(ws + off);                     off += (size_t)N * 4;
    off = (off + 15) & ~(size_t)15;
    float* Pun = (float*)(ws + off);                            off += (size_t)10 * N * 4;
    off = (off + 15) & ~(size_t)15;
    float4* cullv = (float4*)(ws + off);                        off += (size_t)N * 16;
    float4* gA = (float4*)(ws + off);                           off += (size_t)N * 16;
    float4* gB = (float4*)(ws + off);                           off += (size_t)N * 16;
    float4* segbuf = (float4*)(ws + off);
    size_t remain = (ws_size > off) ? (ws_size - off) : 0;
    int nseg = 16;
    while (nseg > 1 && (size_t)nseg * (size_t)HW * 16 > remain) nseg >>= 1;

    k_pre<<<(N + 63) / 64, 64, 0, stream>>>(pws, shs, alphas_raw, scales_raw,
                                            rots_raw, Rcw, tcw, intr, N, W, H,
                                            areas, keys, rank, Pun);
    dim3 rgrid((N + 255) / 256, (N + JC - 1) / JC);
    k_rank_scatter<<<rgrid, 256, 0, stream>>>(keys, N, rank, Pun, gA, gB, cullv);
    int tilesX = (W + 15) / 16, tilesY = (H + 15) / 16;
    int nTiles = tilesX * tilesY;
    k_render<<<nTiles * nseg, 64, 0, stream>>>(gA, gB, cullv, N, W, H,
                                               nTiles, nseg, segbuf);
    k_combine<<<(HW + 255) / 256, 256, 0, stream>>>(segbuf, HW, nseg, out);
}